// Round 1
// baseline (489.015 us; speedup 1.0000x reference)
//
#include <hip/hip_runtime.h>
#include <math.h>

// Sizes (fixed by the reference)
#define N_OBS    20000
#define N_OBS4   5000      // N_OBS/4
#define N_STATES 1024
#define N_ACT    64
#define SDIM     256
#define RFD      2048
#define DECAY    0.9f

// ---------------- workspace layout (floats) ----------------
// s0re[2048] @0, s0im[2048] @2048, s1re @4096, s1im @6144,
// s2re @8192, s2im @10240,
// zeroed region: score[1024] @12288, dot0 @13312 (+3 pad), obs_acc[20000] @13316
// weights[1024] @33316, cosQ[2048*1024] @34816, sinQ @2131968
#define OFF_S0RE   0
#define OFF_S0IM   2048
#define OFF_S1RE   4096
#define OFF_S1IM   6144
#define OFF_S2RE   8192
#define OFF_S2IM   10240
#define OFF_SCORE  12288
#define OFF_DOT0   13312
#define OFF_OBSACC 13316
#define OFF_WTS    33316
#define OFF_COSQ   34816
#define OFF_SINQ   (34816 + RFD*N_STATES)
#define WS_FLOATS  (OFF_SINQ + RFD*N_STATES)
#define ZERO_OFF   OFF_SCORE
#define ZERO_CNT   (OFF_OBSACC + N_OBS - OFF_SCORE)

// K1: state0 = M @ obs  (block per row of M, float4 streaming)
__global__ __launch_bounds__(256) void k_state0(
    const float* __restrict__ Mre, const float* __restrict__ Mim,
    const float* __restrict__ obs, float* __restrict__ s0re, float* __restrict__ s0im)
{
    __shared__ float r1[256], r2[256];
    const int d = blockIdx.x, tid = threadIdx.x;
    const float4* mr = (const float4*)(Mre + (size_t)d * N_OBS);
    const float4* mi = (const float4*)(Mim + (size_t)d * N_OBS);
    const float4* ob = (const float4*)obs;
    float ar = 0.f, ai = 0.f;
    for (int idx = tid; idx < N_OBS4; idx += 256) {
        float4 o = ob[idx];
        float4 a = mr[idx];
        float4 b = mi[idx];
        ar += a.x*o.x + a.y*o.y + a.z*o.z + a.w*o.w;
        ai += b.x*o.x + b.y*o.y + b.z*o.z + b.w*o.w;
    }
    r1[tid] = ar; r2[tid] = ai; __syncthreads();
    for (int s = 128; s > 0; s >>= 1) {
        if (tid < s) { r1[tid] += r1[tid+s]; r2[tid] += r2[tid+s]; }
        __syncthreads();
    }
    if (tid == 0) { s0re[d] = r1[0]; s0im[d] = r2[0]; }
}

// K2: v = V@action (redundant per block); theta_v = W@v; state1 = state0 * e^{i theta_v}
__global__ __launch_bounds__(256) void k_state1(
    const float* __restrict__ V, const float* __restrict__ action,
    const float* __restrict__ W,
    const float* __restrict__ s0re, const float* __restrict__ s0im,
    float* __restrict__ s1re, float* __restrict__ s1im)
{
    __shared__ float vsh[SDIM];
    const int tid = threadIdx.x;
    // v[tid] = sum_a V[tid,a]*action[a]   (V is [256,64] row-major)
    float acc = 0.f;
    for (int a = 0; a < N_ACT; a++) acc += V[tid * N_ACT + a] * action[a];
    vsh[tid] = acc;
    __syncthreads();
    const int d = blockIdx.x * 256 + tid;
    const float* wr = W + (size_t)d * SDIM;
    float th = 0.f;
    #pragma unroll 8
    for (int k = 0; k < SDIM; k++) th += wr[k] * vsh[k];
    float sn, cs;
    sincosf(th, &sn, &cs);
    const float re = s0re[d], im = s0im[d];
    s1re[d] = re * cs - im * sn;
    s1im[d] = re * sn + im * cs;
}

// K3: theta = W@Q tiled GEMM; epilogue: cos/sin stored, score partials accumulated.
// 64x64 tile, 256 threads, 4x4 microtile, BK=16.
__global__ __launch_bounds__(256) void k_phiQ(
    const float* __restrict__ W, const float* __restrict__ Q,
    const float* __restrict__ s1re, const float* __restrict__ s1im,
    float* __restrict__ cosQ, float* __restrict__ sinQ, float* __restrict__ score)
{
    __shared__ float As[16][65];   // [k][m], +1 pad
    __shared__ float Bs[16][64];   // [k][n]
    __shared__ float sscore[64];
    const int tid = threadIdx.x;
    const int tx = tid & 15;       // n-group (4 cols each)
    const int ty = tid >> 4;       // m-group (4 rows each)
    const int m0 = blockIdx.y * 64;
    const int n0 = blockIdx.x * 64;
    float c[4][4] = {};
    for (int k0 = 0; k0 < SDIM; k0 += 16) {
        {   // load A: W[m0+m][k0+k]
            int k = tid & 15, mb = tid >> 4;
            #pragma unroll
            for (int j = 0; j < 4; j++)
                As[k][mb + 16*j] = W[(size_t)(m0 + mb + 16*j) * SDIM + k0 + k];
        }
        {   // load B: Q[k0+k][n0+n]
            int n = tid & 63, kb = tid >> 6;
            #pragma unroll
            for (int j = 0; j < 4; j++)
                Bs[kb + 4*j][n] = Q[(size_t)(k0 + kb + 4*j) * N_STATES + n0 + n];
        }
        __syncthreads();
        #pragma unroll
        for (int kk = 0; kk < 16; kk++) {
            float a[4], b[4];
            #pragma unroll
            for (int i = 0; i < 4; i++) a[i] = As[kk][ty*4 + i];
            #pragma unroll
            for (int j = 0; j < 4; j++) b[j] = Bs[kk][tx*4 + j];
            #pragma unroll
            for (int i = 0; i < 4; i++)
                #pragma unroll
                for (int j = 0; j < 4; j++)
                    c[i][j] += a[i] * b[j];
        }
        __syncthreads();
    }
    if (tid < 64) sscore[tid] = 0.f;
    __syncthreads();
    float sre[4], sim[4];
    #pragma unroll
    for (int i = 0; i < 4; i++) {
        int d = m0 + ty*4 + i;
        sre[i] = s1re[d]; sim[i] = s1im[d];
    }
    #pragma unroll
    for (int j = 0; j < 4; j++) {
        float pj = 0.f;
        #pragma unroll
        for (int i = 0; i < 4; i++) {
            int d = m0 + ty*4 + i;
            int s = n0 + tx*4 + j;
            float sn, cs;
            sincosf(c[i][j], &sn, &cs);
            cosQ[(size_t)d * N_STATES + s] = cs;
            sinQ[(size_t)d * N_STATES + s] = sn;
            pj += cs * sre[i] + sn * sim[i];
        }
        atomicAdd(&sscore[tx*4 + j], pj);
    }
    __syncthreads();
    if (tid < 64) atomicAdd(&score[n0 + tid], sscore[tid]);
}

// K4: weights = softmax(score / 2048), 1024 entries, single block of 256
__global__ __launch_bounds__(256) void k_softmax_w(
    const float* __restrict__ score, float* __restrict__ wts)
{
    __shared__ float red[256];
    const int tid = threadIdx.x;
    const float scale = 1.f / (float)RFD;
    float4 v = ((const float4*)score)[tid];
    v.x *= scale; v.y *= scale; v.z *= scale; v.w *= scale;
    float mx = fmaxf(fmaxf(v.x, v.y), fmaxf(v.z, v.w));
    red[tid] = mx; __syncthreads();
    for (int s = 128; s > 0; s >>= 1) {
        if (tid < s) red[tid] = fmaxf(red[tid], red[tid+s]);
        __syncthreads();
    }
    mx = red[0]; __syncthreads();
    float4 e;
    e.x = expf(v.x - mx); e.y = expf(v.y - mx);
    e.z = expf(v.z - mx); e.w = expf(v.w - mx);
    red[tid] = e.x + e.y + e.z + e.w; __syncthreads();
    for (int s = 128; s > 0; s >>= 1) {
        if (tid < s) red[tid] += red[tid+s];
        __syncthreads();
    }
    const float inv = 1.f / red[0];
    e.x *= inv; e.y *= inv; e.z *= inv; e.w *= inv;
    ((float4*)wts)[tid] = e;
}

// K5: state2 = phi_Q @ weights, plus dot0 = Re(state0 . conj(state2)) via atomics.
// Block per row d.
__global__ __launch_bounds__(256) void k_state2(
    const float* __restrict__ cosQ, const float* __restrict__ sinQ,
    const float* __restrict__ wts,
    const float* __restrict__ s0re, const float* __restrict__ s0im,
    float* __restrict__ s2re, float* __restrict__ s2im, float* __restrict__ dot0)
{
    __shared__ float r1[256], r2[256];
    const int d = blockIdx.x, tid = threadIdx.x;
    float4 w = ((const float4*)wts)[tid];
    float4 a = ((const float4*)(cosQ + (size_t)d * N_STATES))[tid];
    float4 b = ((const float4*)(sinQ + (size_t)d * N_STATES))[tid];
    r1[tid] = a.x*w.x + a.y*w.y + a.z*w.z + a.w*w.w;
    r2[tid] = b.x*w.x + b.y*w.y + b.z*w.z + b.w*w.w;
    __syncthreads();
    for (int s = 128; s > 0; s >>= 1) {
        if (tid < s) { r1[tid] += r1[tid+s]; r2[tid] += r2[tid+s]; }
        __syncthreads();
    }
    if (tid == 0) {
        float rc = r1[0], rs = r2[0];
        s2re[d] = rc; s2im[d] = rs;
        atomicAdd(dot0, s0re[d]*rc + s0im[d]*rs);
    }
}

// K6: obs_acc[o] += sum_{d in chunk} Mre[d,o]*s2re[d] + Mim[d,o]*s2im[d]
// float4 over o; grid (20, 32): x covers 5000 float4s, y covers 32 chunks of 64 rows.
__global__ __launch_bounds__(256) void k_obs_acc(
    const float* __restrict__ Mre, const float* __restrict__ Mim,
    const float* __restrict__ s2re, const float* __restrict__ s2im,
    float* __restrict__ obs_acc)
{
    __shared__ float c_s[64], s_s[64];
    const int tid = threadIdx.x;
    const int dbase = blockIdx.y * 64;
    if (tid < 64) { c_s[tid] = s2re[dbase + tid]; s_s[tid] = s2im[dbase + tid]; }
    __syncthreads();
    const int idx = blockIdx.x * 256 + tid;   // float4 index into a row
    if (idx < N_OBS4) {
        const float4* mr = (const float4*)Mre;
        const float4* mi = (const float4*)Mim;
        float4 acc = make_float4(0.f, 0.f, 0.f, 0.f);
        #pragma unroll 4
        for (int j = 0; j < 64; j++) {
            size_t base = (size_t)(dbase + j) * N_OBS4 + idx;
            float4 a = mr[base];
            float4 b = mi[base];
            float cc = c_s[j], ss = s_s[j];
            acc.x += a.x*cc + b.x*ss;
            acc.y += a.y*cc + b.y*ss;
            acc.z += a.z*cc + b.z*ss;
            acc.w += a.w*cc + b.w*ss;
        }
        atomicAdd(&obs_acc[idx*4 + 0], acc.x);
        atomicAdd(&obs_acc[idx*4 + 1], acc.y);
        atomicAdd(&obs_acc[idx*4 + 2], acc.z);
        atomicAdd(&obs_acc[idx*4 + 3], acc.w);
    }
}

// K7: out = softmax( (0.9*obs_acc + obs*dot0) / 2048 ), 20000 entries, single block 1024.
__global__ __launch_bounds__(1024) void k_softmax_obs(
    const float* __restrict__ obs_acc, const float* __restrict__ obs,
    const float* __restrict__ dot0, float* __restrict__ out)
{
    __shared__ float red[1024];
    const int tid = threadIdx.x;
    const float d0 = *dot0;
    const float scale = 1.f / (float)RFD;
    float vals[20];
    float mx = -3.402823466e+38f;
    #pragma unroll
    for (int i = 0; i < 20; i++) {
        int idx = tid + i * 1024;
        if (idx < N_OBS) {
            float sc = (DECAY * obs_acc[idx] + obs[idx] * d0) * scale;
            vals[i] = sc;
            mx = fmaxf(mx, sc);
        } else vals[i] = -3.402823466e+38f;
    }
    red[tid] = mx; __syncthreads();
    for (int s = 512; s > 0; s >>= 1) {
        if (tid < s) red[tid] = fmaxf(red[tid], red[tid+s]);
        __syncthreads();
    }
    mx = red[0]; __syncthreads();
    float sum = 0.f;
    #pragma unroll
    for (int i = 0; i < 20; i++) {
        int idx = tid + i * 1024;
        if (idx < N_OBS) {
            vals[i] = expf(vals[i] - mx);
            sum += vals[i];
        }
    }
    red[tid] = sum; __syncthreads();
    for (int s = 512; s > 0; s >>= 1) {
        if (tid < s) red[tid] += red[tid+s];
        __syncthreads();
    }
    const float inv = 1.f / red[0];
    #pragma unroll
    for (int i = 0; i < 20; i++) {
        int idx = tid + i * 1024;
        if (idx < N_OBS) out[idx] = vals[i] * inv;
    }
}

extern "C" void kernel_launch(void* const* d_in, const int* in_sizes, int n_in,
                              void* d_out, int out_size, void* d_ws, size_t ws_size,
                              hipStream_t stream) {
    const float* Q      = (const float*)d_in[0];  // [256,1024]
    const float* V      = (const float*)d_in[1];  // [256,64]
    const float* W      = (const float*)d_in[2];  // [2048,256]
    const float* Mre    = (const float*)d_in[3];  // [2048,20000]
    const float* Mim    = (const float*)d_in[4];  // [2048,20000]
    const float* obs    = (const float*)d_in[5];  // [20000]
    const float* action = (const float*)d_in[6];  // [64]
    float* out = (float*)d_out;                   // [20000]
    float* ws  = (float*)d_ws;

    if (ws_size < (size_t)WS_FLOATS * sizeof(float)) return; // need ~16.2 MB scratch

    float* s0re  = ws + OFF_S0RE;
    float* s0im  = ws + OFF_S0IM;
    float* s1re  = ws + OFF_S1RE;
    float* s1im  = ws + OFF_S1IM;
    float* s2re  = ws + OFF_S2RE;
    float* s2im  = ws + OFF_S2IM;
    float* score = ws + OFF_SCORE;
    float* dot0  = ws + OFF_DOT0;
    float* oacc  = ws + OFF_OBSACC;
    float* wts   = ws + OFF_WTS;
    float* cosQ  = ws + OFF_COSQ;
    float* sinQ  = ws + OFF_SINQ;

    // zero the atomic accumulators (score, dot0, obs_acc) in one contiguous memset
    hipMemsetAsync(ws + ZERO_OFF, 0, (size_t)ZERO_CNT * sizeof(float), stream);

    k_state0<<<RFD, 256, 0, stream>>>(Mre, Mim, obs, s0re, s0im);
    k_state1<<<RFD / 256, 256, 0, stream>>>(V, action, W, s0re, s0im, s1re, s1im);
    k_phiQ<<<dim3(N_STATES / 64, RFD / 64), 256, 0, stream>>>(W, Q, s1re, s1im, cosQ, sinQ, score);
    k_softmax_w<<<1, 256, 0, stream>>>(score, wts);
    k_state2<<<RFD, 256, 0, stream>>>(cosQ, sinQ, wts, s0re, s0im, s2re, s2im, dot0);
    k_obs_acc<<<dim3((N_OBS4 + 255) / 256, RFD / 64), 256, 0, stream>>>(Mre, Mim, s2re, s2im, oacc);
    k_softmax_obs<<<1, 1024, 0, stream>>>(oacc, obs, dot0, out);
}

// Round 2
// 469.630 us; speedup vs baseline: 1.0413x; 1.0413x over previous
//
#include <hip/hip_runtime.h>
#include <math.h>

// Sizes (fixed by the reference)
#define N_OBS    20000
#define N_OBS4   5000      // N_OBS/4
#define N_STATES 1024
#define N_ACT    64
#define SDIM     256
#define RFD      2048
#define DECAY    0.9f

// ---------------- workspace layout (floats) ----------------
// zeroed region @0: s0re[2048], s0im[2048], score[1024], obs_acc[20000]
#define OFF_S0RE   0
#define OFF_S0IM   2048
#define OFF_SCORE  4096
#define OFF_OBSACC 5120
#define ZERO_CNT   (OFF_OBSACC + N_OBS)           // 25120 floats
#define OFF_S1RE   25120
#define OFF_S1IM   27168
#define OFF_S2RE   29216
#define OFF_S2IM   31264
#define OFF_WTS    33312
#define OFF_COSQ   34816
#define OFF_SINQ   (34816 + RFD*N_STATES)
#define WS_FLOATS  (OFF_SINQ + RFD*N_STATES)      // ~16.9 MB

// K1: state0 = M @ obs. Row split into 10 segments of 500 float4s.
// grid (10, 2048), 256 threads. Wave-shuffle reduce + atomicAdd partials.
__global__ __launch_bounds__(256) void k_state0(
    const float* __restrict__ Mre, const float* __restrict__ Mim,
    const float* __restrict__ obs, float* __restrict__ s0re, float* __restrict__ s0im)
{
    const int d = blockIdx.y;
    const int seg = blockIdx.x;          // 0..9
    const int tid = threadIdx.x;
    const float4* mr = (const float4*)(Mre + (size_t)d * N_OBS) + seg * 500;
    const float4* mi = (const float4*)(Mim + (size_t)d * N_OBS) + seg * 500;
    const float4* ob = (const float4*)obs + seg * 500;
    float ar = 0.f, ai = 0.f;
    #pragma unroll
    for (int it = 0; it < 2; ++it) {
        int i = tid + it * 256;
        if (i < 500) {
            float4 o = ob[i];
            float4 a = mr[i];
            float4 b = mi[i];
            ar += a.x*o.x + a.y*o.y + a.z*o.z + a.w*o.w;
            ai += b.x*o.x + b.y*o.y + b.z*o.z + b.w*o.w;
        }
    }
    #pragma unroll
    for (int off = 32; off > 0; off >>= 1) {
        ar += __shfl_down(ar, off);
        ai += __shfl_down(ai, off);
    }
    __shared__ float pr[4], pi[4];
    const int wave = tid >> 6, lane = tid & 63;
    if (lane == 0) { pr[wave] = ar; pi[wave] = ai; }
    __syncthreads();
    if (tid == 0) {
        atomicAdd(&s0re[d], pr[0] + pr[1] + pr[2] + pr[3]);
        atomicAdd(&s0im[d], pi[0] + pi[1] + pi[2] + pi[3]);
    }
}

// K2: v = V@action (redundant per block); theta_v = W@v; state1 = state0 * e^{i theta_v}
__global__ __launch_bounds__(256) void k_state1(
    const float* __restrict__ V, const float* __restrict__ action,
    const float* __restrict__ W,
    const float* __restrict__ s0re, const float* __restrict__ s0im,
    float* __restrict__ s1re, float* __restrict__ s1im)
{
    __shared__ float vsh[SDIM];
    const int tid = threadIdx.x;
    float acc = 0.f;
    for (int a = 0; a < N_ACT; a++) acc += V[tid * N_ACT + a] * action[a];
    vsh[tid] = acc;
    __syncthreads();
    const int d = blockIdx.x * 256 + tid;
    const float* wr = W + (size_t)d * SDIM;
    float th = 0.f;
    #pragma unroll 8
    for (int k = 0; k < SDIM; k++) th += wr[k] * vsh[k];
    float sn, cs;
    sincosf(th, &sn, &cs);
    const float re = s0re[d], im = s0im[d];
    s1re[d] = re * cs - im * sn;
    s1im[d] = re * sn + im * cs;
}

// K3: theta = W@Q tiled GEMM; epilogue: cos/sin stored, score partials accumulated.
__global__ __launch_bounds__(256) void k_phiQ(
    const float* __restrict__ W, const float* __restrict__ Q,
    const float* __restrict__ s1re, const float* __restrict__ s1im,
    float* __restrict__ cosQ, float* __restrict__ sinQ, float* __restrict__ score)
{
    __shared__ float As[16][65];   // [k][m], +1 pad
    __shared__ float Bs[16][64];   // [k][n]
    __shared__ float sscore[64];
    const int tid = threadIdx.x;
    const int tx = tid & 15;       // n-group (4 cols each)
    const int ty = tid >> 4;       // m-group (4 rows each)
    const int m0 = blockIdx.y * 64;
    const int n0 = blockIdx.x * 64;
    float c[4][4] = {};
    for (int k0 = 0; k0 < SDIM; k0 += 16) {
        {   // load A: W[m0+m][k0+k]
            int k = tid & 15, mb = tid >> 4;
            #pragma unroll
            for (int j = 0; j < 4; j++)
                As[k][mb + 16*j] = W[(size_t)(m0 + mb + 16*j) * SDIM + k0 + k];
        }
        {   // load B: Q[k0+k][n0+n]
            int n = tid & 63, kb = tid >> 6;
            #pragma unroll
            for (int j = 0; j < 4; j++)
                Bs[kb + 4*j][n] = Q[(size_t)(k0 + kb + 4*j) * N_STATES + n0 + n];
        }
        __syncthreads();
        #pragma unroll
        for (int kk = 0; kk < 16; kk++) {
            float a[4], b[4];
            #pragma unroll
            for (int i = 0; i < 4; i++) a[i] = As[kk][ty*4 + i];
            #pragma unroll
            for (int j = 0; j < 4; j++) b[j] = Bs[kk][tx*4 + j];
            #pragma unroll
            for (int i = 0; i < 4; i++)
                #pragma unroll
                for (int j = 0; j < 4; j++)
                    c[i][j] += a[i] * b[j];
        }
        __syncthreads();
    }
    if (tid < 64) sscore[tid] = 0.f;
    __syncthreads();
    float sre[4], sim[4];
    #pragma unroll
    for (int i = 0; i < 4; i++) {
        int d = m0 + ty*4 + i;
        sre[i] = s1re[d]; sim[i] = s1im[d];
    }
    #pragma unroll
    for (int j = 0; j < 4; j++) {
        float pj = 0.f;
        #pragma unroll
        for (int i = 0; i < 4; i++) {
            int d = m0 + ty*4 + i;
            int s = n0 + tx*4 + j;
            float sn, cs;
            sincosf(c[i][j], &sn, &cs);
            cosQ[(size_t)d * N_STATES + s] = cs;
            sinQ[(size_t)d * N_STATES + s] = sn;
            pj += cs * sre[i] + sn * sim[i];
        }
        atomicAdd(&sscore[tx*4 + j], pj);
    }
    __syncthreads();
    if (tid < 64) atomicAdd(&score[n0 + tid], sscore[tid]);
}

// K4: weights = softmax(score / 2048), 1024 entries, single block of 256
__global__ __launch_bounds__(256) void k_softmax_w(
    const float* __restrict__ score, float* __restrict__ wts)
{
    __shared__ float red[256];
    const int tid = threadIdx.x;
    const float scale = 1.f / (float)RFD;
    float4 v = ((const float4*)score)[tid];
    v.x *= scale; v.y *= scale; v.z *= scale; v.w *= scale;
    float mx = fmaxf(fmaxf(v.x, v.y), fmaxf(v.z, v.w));
    red[tid] = mx; __syncthreads();
    for (int s = 128; s > 0; s >>= 1) {
        if (tid < s) red[tid] = fmaxf(red[tid], red[tid+s]);
        __syncthreads();
    }
    mx = red[0]; __syncthreads();
    float4 e;
    e.x = expf(v.x - mx); e.y = expf(v.y - mx);
    e.z = expf(v.z - mx); e.w = expf(v.w - mx);
    red[tid] = e.x + e.y + e.z + e.w; __syncthreads();
    for (int s = 128; s > 0; s >>= 1) {
        if (tid < s) red[tid] += red[tid+s];
        __syncthreads();
    }
    const float inv = 1.f / red[0];
    e.x *= inv; e.y *= inv; e.z *= inv; e.w *= inv;
    ((float4*)wts)[tid] = e;
}

// K5: state2 = phi_Q @ weights. Block per row d.
__global__ __launch_bounds__(256) void k_state2(
    const float* __restrict__ cosQ, const float* __restrict__ sinQ,
    const float* __restrict__ wts,
    float* __restrict__ s2re, float* __restrict__ s2im)
{
    __shared__ float r1[256], r2[256];
    const int d = blockIdx.x, tid = threadIdx.x;
    float4 w = ((const float4*)wts)[tid];
    float4 a = ((const float4*)(cosQ + (size_t)d * N_STATES))[tid];
    float4 b = ((const float4*)(sinQ + (size_t)d * N_STATES))[tid];
    r1[tid] = a.x*w.x + a.y*w.y + a.z*w.z + a.w*w.w;
    r2[tid] = b.x*w.x + b.y*w.y + b.z*w.z + b.w*w.w;
    __syncthreads();
    for (int s = 128; s > 0; s >>= 1) {
        if (tid < s) { r1[tid] += r1[tid+s]; r2[tid] += r2[tid+s]; }
        __syncthreads();
    }
    if (tid == 0) { s2re[d] = r1[0]; s2im[d] = r2[0]; }
}

// K6: obs_acc[o] += sum_{d in chunk of 32} Mre[d,o]*s2re[d] + Mim[d,o]*s2im[d]
// grid (20, 64), 256 threads, float4 over o.
__global__ __launch_bounds__(256) void k_obs_acc(
    const float* __restrict__ Mre, const float* __restrict__ Mim,
    const float* __restrict__ s2re, const float* __restrict__ s2im,
    float* __restrict__ obs_acc)
{
    __shared__ float c_s[32], s_s[32];
    const int tid = threadIdx.x;
    const int dbase = blockIdx.y * 32;
    if (tid < 32) { c_s[tid] = s2re[dbase + tid]; s_s[tid] = s2im[dbase + tid]; }
    __syncthreads();
    const int idx = blockIdx.x * 256 + tid;   // float4 index into a row
    if (idx < N_OBS4) {
        const float4* mr = (const float4*)Mre;
        const float4* mi = (const float4*)Mim;
        float4 acc = make_float4(0.f, 0.f, 0.f, 0.f);
        #pragma unroll 8
        for (int j = 0; j < 32; j++) {
            size_t base = (size_t)(dbase + j) * N_OBS4 + idx;
            float4 a = mr[base];
            float4 b = mi[base];
            float cc = c_s[j], ss = s_s[j];
            acc.x += a.x*cc + b.x*ss;
            acc.y += a.y*cc + b.y*ss;
            acc.z += a.z*cc + b.z*ss;
            acc.w += a.w*cc + b.w*ss;
        }
        atomicAdd(&obs_acc[idx*4 + 0], acc.x);
        atomicAdd(&obs_acc[idx*4 + 1], acc.y);
        atomicAdd(&obs_acc[idx*4 + 2], acc.z);
        atomicAdd(&obs_acc[idx*4 + 3], acc.w);
    }
}

// K7: dot0 = Re(s0 . conj(s2)); out = softmax((0.9*obs_acc + obs*dot0)/2048).
// Single block of 1024.
__global__ __launch_bounds__(1024) void k_softmax_obs(
    const float* __restrict__ obs_acc, const float* __restrict__ obs,
    const float* __restrict__ s0re, const float* __restrict__ s0im,
    const float* __restrict__ s2re, const float* __restrict__ s2im,
    float* __restrict__ out)
{
    __shared__ float red[1024];
    const int tid = threadIdx.x;
    // dot0 = sum_d s0re*s2re + s0im*s2im
    float dp = 0.f;
    #pragma unroll
    for (int i = 0; i < 2; i++) {
        int d = tid + i * 1024;
        dp += s0re[d] * s2re[d] + s0im[d] * s2im[d];
    }
    red[tid] = dp; __syncthreads();
    for (int s = 512; s > 0; s >>= 1) {
        if (tid < s) red[tid] += red[tid+s];
        __syncthreads();
    }
    const float d0 = red[0];
    __syncthreads();
    const float scale = 1.f / (float)RFD;
    float vals[20];
    float mx = -3.402823466e+38f;
    #pragma unroll
    for (int i = 0; i < 20; i++) {
        int idx = tid + i * 1024;
        if (idx < N_OBS) {
            float sc = (DECAY * obs_acc[idx] + obs[idx] * d0) * scale;
            vals[i] = sc;
            mx = fmaxf(mx, sc);
        } else vals[i] = -3.402823466e+38f;
    }
    red[tid] = mx; __syncthreads();
    for (int s = 512; s > 0; s >>= 1) {
        if (tid < s) red[tid] = fmaxf(red[tid], red[tid+s]);
        __syncthreads();
    }
    mx = red[0]; __syncthreads();
    float sum = 0.f;
    #pragma unroll
    for (int i = 0; i < 20; i++) {
        int idx = tid + i * 1024;
        if (idx < N_OBS) {
            vals[i] = expf(vals[i] - mx);
            sum += vals[i];
        }
    }
    red[tid] = sum; __syncthreads();
    for (int s = 512; s > 0; s >>= 1) {
        if (tid < s) red[tid] += red[tid+s];
        __syncthreads();
    }
    const float inv = 1.f / red[0];
    #pragma unroll
    for (int i = 0; i < 20; i++) {
        int idx = tid + i * 1024;
        if (idx < N_OBS) out[idx] = vals[i] * inv;
    }
}

extern "C" void kernel_launch(void* const* d_in, const int* in_sizes, int n_in,
                              void* d_out, int out_size, void* d_ws, size_t ws_size,
                              hipStream_t stream) {
    const float* Q      = (const float*)d_in[0];  // [256,1024]
    const float* V      = (const float*)d_in[1];  // [256,64]
    const float* W      = (const float*)d_in[2];  // [2048,256]
    const float* Mre    = (const float*)d_in[3];  // [2048,20000]
    const float* Mim    = (const float*)d_in[4];  // [2048,20000]
    const float* obs    = (const float*)d_in[5];  // [20000]
    const float* action = (const float*)d_in[6];  // [64]
    float* out = (float*)d_out;                   // [20000]
    float* ws  = (float*)d_ws;

    if (ws_size < (size_t)WS_FLOATS * sizeof(float)) return;

    float* s0re  = ws + OFF_S0RE;
    float* s0im  = ws + OFF_S0IM;
    float* score = ws + OFF_SCORE;
    float* oacc  = ws + OFF_OBSACC;
    float* s1re  = ws + OFF_S1RE;
    float* s1im  = ws + OFF_S1IM;
    float* s2re  = ws + OFF_S2RE;
    float* s2im  = ws + OFF_S2IM;
    float* wts   = ws + OFF_WTS;
    float* cosQ  = ws + OFF_COSQ;
    float* sinQ  = ws + OFF_SINQ;

    // zero the atomic accumulators (s0, score, obs_acc) in one contiguous memset
    hipMemsetAsync(ws, 0, (size_t)ZERO_CNT * sizeof(float), stream);

    k_state0<<<dim3(10, RFD), 256, 0, stream>>>(Mre, Mim, obs, s0re, s0im);
    k_state1<<<RFD / 256, 256, 0, stream>>>(V, action, W, s0re, s0im, s1re, s1im);
    k_phiQ<<<dim3(N_STATES / 64, RFD / 64), 256, 0, stream>>>(W, Q, s1re, s1im, cosQ, sinQ, score);
    k_softmax_w<<<1, 256, 0, stream>>>(score, wts);
    k_state2<<<RFD, 256, 0, stream>>>(cosQ, sinQ, wts, s2re, s2im);
    k_obs_acc<<<dim3((N_OBS4 + 255) / 256, RFD / 32), 256, 0, stream>>>(Mre, Mim, s2re, s2im, oacc);
    k_softmax_obs<<<1, 1024, 0, stream>>>(oacc, obs, s0re, s0im, s2re, s2im, out);
}

// Round 3
// 442.661 us; speedup vs baseline: 1.1047x; 1.0609x over previous
//
#include <hip/hip_runtime.h>
#include <math.h>

// Sizes (fixed by the reference)
#define N_OBS    20000
#define N_OBS4   5000      // N_OBS/4
#define N_STATES 1024
#define N_ACT    64
#define SDIM     256
#define RFD      2048
#define DECAY    0.9f

typedef float v4f __attribute__((ext_vector_type(4)));

__device__ __forceinline__ v4f ntload4(const float* p) {
    return __builtin_nontemporal_load((const v4f*)p);
}

// ---------------- workspace layout (floats) ----------------
// zeroed region @0: score[1024], obs_acc[20000]
#define OFF_SCORE  0
#define OFF_OBSACC 1024
#define ZERO_CNT   (OFF_OBSACC + N_OBS)           // 21024 floats
#define OFF_S0RE   21024
#define OFF_S0IM   23072
#define OFF_S1RE   25120
#define OFF_S1IM   27168
#define OFF_S2RE   29216
#define OFF_S2IM   31264
#define OFF_WTS    33312
#define OFF_COSQ   34816
#define OFF_SINQ   (34816 + RFD*N_STATES)
#define WS_FLOATS  (OFF_SINQ + RFD*N_STATES)      // ~16.9 MB
// state0 partials [10][2048] re+im alias the cosQ region (dead until k_phiQ)
#define OFF_P0RE   OFF_COSQ
#define OFF_P0IM   (OFF_COSQ + 10*RFD)

// K1: state0 partials. Row split into 10 segments of 500 float4s.
// grid (10, 2048), 256 threads. Non-temporal M loads; partials to ws (no atomics).
__global__ __launch_bounds__(256) void k_state0(
    const float* __restrict__ Mre, const float* __restrict__ Mim,
    const float* __restrict__ obs, float* __restrict__ p0re, float* __restrict__ p0im)
{
    const int d = blockIdx.y;
    const int seg = blockIdx.x;          // 0..9
    const int tid = threadIdx.x;
    const float* mr = Mre + (size_t)d * N_OBS + seg * 2000;
    const float* mi = Mim + (size_t)d * N_OBS + seg * 2000;
    const float4* ob = (const float4*)obs + seg * 500;
    float ar = 0.f, ai = 0.f;
    #pragma unroll
    for (int it = 0; it < 2; ++it) {
        int i = tid + it * 256;
        if (i < 500) {
            float4 o = ob[i];
            v4f a = ntload4(mr + i * 4);
            v4f b = ntload4(mi + i * 4);
            ar += a.x*o.x + a.y*o.y + a.z*o.z + a.w*o.w;
            ai += b.x*o.x + b.y*o.y + b.z*o.z + b.w*o.w;
        }
    }
    #pragma unroll
    for (int off = 32; off > 0; off >>= 1) {
        ar += __shfl_down(ar, off);
        ai += __shfl_down(ai, off);
    }
    __shared__ float pr[4], pi[4];
    const int wave = tid >> 6, lane = tid & 63;
    if (lane == 0) { pr[wave] = ar; pi[wave] = ai; }
    __syncthreads();
    if (tid == 0) {
        p0re[seg * RFD + d] = pr[0] + pr[1] + pr[2] + pr[3];
        p0im[seg * RFD + d] = pi[0] + pi[1] + pi[2] + pi[3];
    }
}

// K2: sum state0 partials; v = V@action (redundant per block); theta_v = W@v;
// state1 = state0 * e^{i theta_v}. Also writes final s0 (for dot0 later).
__global__ __launch_bounds__(256) void k_state1(
    const float* __restrict__ V, const float* __restrict__ action,
    const float* __restrict__ W,
    const float* __restrict__ p0re, const float* __restrict__ p0im,
    float* __restrict__ s0re, float* __restrict__ s0im,
    float* __restrict__ s1re, float* __restrict__ s1im)
{
    __shared__ float vsh[SDIM];
    const int tid = threadIdx.x;
    float acc = 0.f;
    for (int a = 0; a < N_ACT; a++) acc += V[tid * N_ACT + a] * action[a];
    vsh[tid] = acc;
    __syncthreads();
    const int d = blockIdx.x * 256 + tid;
    float re = 0.f, im = 0.f;
    #pragma unroll
    for (int s = 0; s < 10; s++) {
        re += p0re[s * RFD + d];
        im += p0im[s * RFD + d];
    }
    s0re[d] = re; s0im[d] = im;
    const float* wr = W + (size_t)d * SDIM;
    float th = 0.f;
    #pragma unroll 8
    for (int k = 0; k < SDIM; k++) th += wr[k] * vsh[k];
    float sn, cs;
    sincosf(th, &sn, &cs);
    s1re[d] = re * cs - im * sn;
    s1im[d] = re * sn + im * cs;
}

// K3: theta = W@Q tiled GEMM; epilogue: cos/sin stored, score partials accumulated.
__global__ __launch_bounds__(256) void k_phiQ(
    const float* __restrict__ W, const float* __restrict__ Q,
    const float* __restrict__ s1re, const float* __restrict__ s1im,
    float* __restrict__ cosQ, float* __restrict__ sinQ, float* __restrict__ score)
{
    __shared__ float As[16][65];   // [k][m], +1 pad
    __shared__ float Bs[16][64];   // [k][n]
    __shared__ float sscore[64];
    const int tid = threadIdx.x;
    const int tx = tid & 15;       // n-group (4 cols each)
    const int ty = tid >> 4;       // m-group (4 rows each)
    const int m0 = blockIdx.y * 64;
    const int n0 = blockIdx.x * 64;
    float c[4][4] = {};
    for (int k0 = 0; k0 < SDIM; k0 += 16) {
        {   // load A: W[m0+m][k0+k]
            int k = tid & 15, mb = tid >> 4;
            #pragma unroll
            for (int j = 0; j < 4; j++)
                As[k][mb + 16*j] = W[(size_t)(m0 + mb + 16*j) * SDIM + k0 + k];
        }
        {   // load B: Q[k0+k][n0+n]
            int n = tid & 63, kb = tid >> 6;
            #pragma unroll
            for (int j = 0; j < 4; j++)
                Bs[kb + 4*j][n] = Q[(size_t)(k0 + kb + 4*j) * N_STATES + n0 + n];
        }
        __syncthreads();
        #pragma unroll
        for (int kk = 0; kk < 16; kk++) {
            float a[4], b[4];
            #pragma unroll
            for (int i = 0; i < 4; i++) a[i] = As[kk][ty*4 + i];
            #pragma unroll
            for (int j = 0; j < 4; j++) b[j] = Bs[kk][tx*4 + j];
            #pragma unroll
            for (int i = 0; i < 4; i++)
                #pragma unroll
                for (int j = 0; j < 4; j++)
                    c[i][j] += a[i] * b[j];
        }
        __syncthreads();
    }
    if (tid < 64) sscore[tid] = 0.f;
    __syncthreads();
    float sre[4], sim[4];
    #pragma unroll
    for (int i = 0; i < 4; i++) {
        int d = m0 + ty*4 + i;
        sre[i] = s1re[d]; sim[i] = s1im[d];
    }
    #pragma unroll
    for (int j = 0; j < 4; j++) {
        float pj = 0.f;
        #pragma unroll
        for (int i = 0; i < 4; i++) {
            int d = m0 + ty*4 + i;
            int s = n0 + tx*4 + j;
            float sn, cs;
            sincosf(c[i][j], &sn, &cs);
            cosQ[(size_t)d * N_STATES + s] = cs;
            sinQ[(size_t)d * N_STATES + s] = sn;
            pj += cs * sre[i] + sn * sim[i];
        }
        atomicAdd(&sscore[tx*4 + j], pj);
    }
    __syncthreads();
    if (tid < 64) atomicAdd(&score[n0 + tid], sscore[tid]);
}

// K4: weights = softmax(score / 2048), 1024 entries, single block of 256
__global__ __launch_bounds__(256) void k_softmax_w(
    const float* __restrict__ score, float* __restrict__ wts)
{
    __shared__ float red[256];
    const int tid = threadIdx.x;
    const float scale = 1.f / (float)RFD;
    float4 v = ((const float4*)score)[tid];
    v.x *= scale; v.y *= scale; v.z *= scale; v.w *= scale;
    float mx = fmaxf(fmaxf(v.x, v.y), fmaxf(v.z, v.w));
    red[tid] = mx; __syncthreads();
    for (int s = 128; s > 0; s >>= 1) {
        if (tid < s) red[tid] = fmaxf(red[tid], red[tid+s]);
        __syncthreads();
    }
    mx = red[0]; __syncthreads();
    float4 e;
    e.x = expf(v.x - mx); e.y = expf(v.y - mx);
    e.z = expf(v.z - mx); e.w = expf(v.w - mx);
    red[tid] = e.x + e.y + e.z + e.w; __syncthreads();
    for (int s = 128; s > 0; s >>= 1) {
        if (tid < s) red[tid] += red[tid+s];
        __syncthreads();
    }
    const float inv = 1.f / red[0];
    e.x *= inv; e.y *= inv; e.z *= inv; e.w *= inv;
    ((float4*)wts)[tid] = e;
}

// K5: state2 = phi_Q @ weights. Block per row d.
__global__ __launch_bounds__(256) void k_state2(
    const float* __restrict__ cosQ, const float* __restrict__ sinQ,
    const float* __restrict__ wts,
    float* __restrict__ s2re, float* __restrict__ s2im)
{
    __shared__ float r1[256], r2[256];
    const int d = blockIdx.x, tid = threadIdx.x;
    float4 w = ((const float4*)wts)[tid];
    float4 a = ((const float4*)(cosQ + (size_t)d * N_STATES))[tid];
    float4 b = ((const float4*)(sinQ + (size_t)d * N_STATES))[tid];
    r1[tid] = a.x*w.x + a.y*w.y + a.z*w.z + a.w*w.w;
    r2[tid] = b.x*w.x + b.y*w.y + b.z*w.z + b.w*w.w;
    __syncthreads();
    for (int s = 128; s > 0; s >>= 1) {
        if (tid < s) { r1[tid] += r1[tid+s]; r2[tid] += r2[tid+s]; }
        __syncthreads();
    }
    if (tid == 0) { s2re[d] = r1[0]; s2im[d] = r2[0]; }
}

// K6: obs_acc[o] += sum_{d in chunk of 32} Mre[d,o]*s2re[d] + Mim[d,o]*s2im[d]
// grid (20, 64), 256 threads, float4 over o, non-temporal M loads.
__global__ __launch_bounds__(256) void k_obs_acc(
    const float* __restrict__ Mre, const float* __restrict__ Mim,
    const float* __restrict__ s2re, const float* __restrict__ s2im,
    float* __restrict__ obs_acc)
{
    __shared__ float c_s[32], s_s[32];
    const int tid = threadIdx.x;
    const int dbase = blockIdx.y * 32;
    if (tid < 32) { c_s[tid] = s2re[dbase + tid]; s_s[tid] = s2im[dbase + tid]; }
    __syncthreads();
    const int idx = blockIdx.x * 256 + tid;   // float4 index into a row
    if (idx < N_OBS4) {
        float4 acc = make_float4(0.f, 0.f, 0.f, 0.f);
        #pragma unroll 8
        for (int j = 0; j < 32; j++) {
            size_t base = ((size_t)(dbase + j) * N_OBS4 + idx) * 4;
            v4f a = ntload4(Mre + base);
            v4f b = ntload4(Mim + base);
            float cc = c_s[j], ss = s_s[j];
            acc.x += a.x*cc + b.x*ss;
            acc.y += a.y*cc + b.y*ss;
            acc.z += a.z*cc + b.z*ss;
            acc.w += a.w*cc + b.w*ss;
        }
        atomicAdd(&obs_acc[idx*4 + 0], acc.x);
        atomicAdd(&obs_acc[idx*4 + 1], acc.y);
        atomicAdd(&obs_acc[idx*4 + 2], acc.z);
        atomicAdd(&obs_acc[idx*4 + 3], acc.w);
    }
}

// K7: dot0 = Re(s0 . conj(s2)); out = softmax((0.9*obs_acc + obs*dot0)/2048).
// Single block of 1024.
__global__ __launch_bounds__(1024) void k_softmax_obs(
    const float* __restrict__ obs_acc, const float* __restrict__ obs,
    const float* __restrict__ s0re, const float* __restrict__ s0im,
    const float* __restrict__ s2re, const float* __restrict__ s2im,
    float* __restrict__ out)
{
    __shared__ float red[1024];
    const int tid = threadIdx.x;
    float dp = 0.f;
    #pragma unroll
    for (int i = 0; i < 2; i++) {
        int d = tid + i * 1024;
        dp += s0re[d] * s2re[d] + s0im[d] * s2im[d];
    }
    red[tid] = dp; __syncthreads();
    for (int s = 512; s > 0; s >>= 1) {
        if (tid < s) red[tid] += red[tid+s];
        __syncthreads();
    }
    const float d0 = red[0];
    __syncthreads();
    const float scale = 1.f / (float)RFD;
    float vals[20];
    float mx = -3.402823466e+38f;
    #pragma unroll
    for (int i = 0; i < 20; i++) {
        int idx = tid + i * 1024;
        if (idx < N_OBS) {
            float sc = (DECAY * obs_acc[idx] + obs[idx] * d0) * scale;
            vals[i] = sc;
            mx = fmaxf(mx, sc);
        } else vals[i] = -3.402823466e+38f;
    }
    red[tid] = mx; __syncthreads();
    for (int s = 512; s > 0; s >>= 1) {
        if (tid < s) red[tid] = fmaxf(red[tid], red[tid+s]);
        __syncthreads();
    }
    mx = red[0]; __syncthreads();
    float sum = 0.f;
    #pragma unroll
    for (int i = 0; i < 20; i++) {
        int idx = tid + i * 1024;
        if (idx < N_OBS) {
            vals[i] = expf(vals[i] - mx);
            sum += vals[i];
        }
    }
    red[tid] = sum; __syncthreads();
    for (int s = 512; s > 0; s >>= 1) {
        if (tid < s) red[tid] += red[tid+s];
        __syncthreads();
    }
    const float inv = 1.f / red[0];
    #pragma unroll
    for (int i = 0; i < 20; i++) {
        int idx = tid + i * 1024;
        if (idx < N_OBS) out[idx] = vals[i] * inv;
    }
}

extern "C" void kernel_launch(void* const* d_in, const int* in_sizes, int n_in,
                              void* d_out, int out_size, void* d_ws, size_t ws_size,
                              hipStream_t stream) {
    const float* Q      = (const float*)d_in[0];  // [256,1024]
    const float* V      = (const float*)d_in[1];  // [256,64]
    const float* W      = (const float*)d_in[2];  // [2048,256]
    const float* Mre    = (const float*)d_in[3];  // [2048,20000]
    const float* Mim    = (const float*)d_in[4];  // [2048,20000]
    const float* obs    = (const float*)d_in[5];  // [20000]
    const float* action = (const float*)d_in[6];  // [64]
    float* out = (float*)d_out;                   // [20000]
    float* ws  = (float*)d_ws;

    if (ws_size < (size_t)WS_FLOATS * sizeof(float)) return;

    float* score = ws + OFF_SCORE;
    float* oacc  = ws + OFF_OBSACC;
    float* s0re  = ws + OFF_S0RE;
    float* s0im  = ws + OFF_S0IM;
    float* s1re  = ws + OFF_S1RE;
    float* s1im  = ws + OFF_S1IM;
    float* s2re  = ws + OFF_S2RE;
    float* s2im  = ws + OFF_S2IM;
    float* wts   = ws + OFF_WTS;
    float* cosQ  = ws + OFF_COSQ;
    float* sinQ  = ws + OFF_SINQ;
    float* p0re  = ws + OFF_P0RE;   // aliases cosQ region (dead until k_phiQ)
    float* p0im  = ws + OFF_P0IM;

    // zero the atomic accumulators (score, obs_acc) in one contiguous memset
    hipMemsetAsync(ws, 0, (size_t)ZERO_CNT * sizeof(float), stream);

    k_state0<<<dim3(10, RFD), 256, 0, stream>>>(Mre, Mim, obs, p0re, p0im);
    k_state1<<<RFD / 256, 256, 0, stream>>>(V, action, W, p0re, p0im, s0re, s0im, s1re, s1im);
    k_phiQ<<<dim3(N_STATES / 64, RFD / 64), 256, 0, stream>>>(W, Q, s1re, s1im, cosQ, sinQ, score);
    k_softmax_w<<<1, 256, 0, stream>>>(score, wts);
    k_state2<<<RFD, 256, 0, stream>>>(cosQ, sinQ, wts, s2re, s2im);
    k_obs_acc<<<dim3((N_OBS4 + 255) / 256, RFD / 32), 256, 0, stream>>>(Mre, Mim, s2re, s2im, oacc);
    k_softmax_obs<<<1, 1024, 0, stream>>>(oacc, obs, s0re, s0im, s2re, s2im, out);
}

// Round 4
// 421.322 us; speedup vs baseline: 1.1607x; 1.0506x over previous
//
#include <hip/hip_runtime.h>
#include <math.h>

// Sizes (fixed by the reference)
#define N_OBS    20000
#define N_OBS4   5000      // N_OBS/4
#define N_STATES 1024
#define N_ACT    64
#define SDIM     256
#define RFD      2048
#define DECAY    0.9f

typedef float v4f __attribute__((ext_vector_type(4)));

__device__ __forceinline__ v4f ntload4(const float* p) {
    return __builtin_nontemporal_load((const v4f*)p);
}

// ---------------- workspace layout (floats) ----------------
// zeroed region @0: score[1024], obs_acc[20000]
#define OFF_SCORE  0
#define OFF_OBSACC 1024
#define ZERO_CNT   (OFF_OBSACC + N_OBS)           // 21024 floats
#define OFF_S0RE   21024
#define OFF_S0IM   23072
#define OFF_S1RE   25120
#define OFF_S1IM   27168
#define OFF_S2RE   29216
#define OFF_S2IM   31264
#define OFF_WTS    33312
#define OFF_VWS    34336
#define OFF_COSQ   34816
#define OFF_SINQ   (OFF_COSQ + RFD*N_STATES)
#define OFF_P0RE   (OFF_SINQ + RFD*N_STATES)      // [5][2048]
#define OFF_P0IM   (OFF_P0RE + 5*RFD)
#define WS_FLOATS  (OFF_P0IM + 5*RFD)             // ~17 MB

// Fused kernel: blocks 0..511 = W@Q GEMM tiles (cos/sin), block 512 = v=V@action,
// blocks 513..10752 = state0 partials (5 segs x 2048 rows).
#define NB_GEMM   512
#define NB_STATE0 (5 * RFD)
#define NB_FUSED  (NB_GEMM + 1 + NB_STATE0)

__global__ __launch_bounds__(256) void k_fused(
    const float* __restrict__ Mre, const float* __restrict__ Mim,
    const float* __restrict__ obs,
    const float* __restrict__ W, const float* __restrict__ Q,
    const float* __restrict__ V, const float* __restrict__ action,
    float* __restrict__ cosQ, float* __restrict__ sinQ,
    float* __restrict__ p0re, float* __restrict__ p0im,
    float* __restrict__ vout)
{
    const int b = blockIdx.x;
    const int tid = threadIdx.x;

    if (b < NB_GEMM) {
        // ---- W@Q GEMM tile: theta -> cos/sin (no score here) ----
        __shared__ float As[16][65];   // [k][m], +1 pad
        __shared__ float Bs[16][64];   // [k][n]
        const int tx = tid & 15;       // n-group (4 cols each)
        const int ty = tid >> 4;       // m-group (4 rows each)
        const int m0 = (b >> 4) * 64;  // 32 m-tiles
        const int n0 = (b & 15) * 64;  // 16 n-tiles
        float c[4][4] = {};
        for (int k0 = 0; k0 < SDIM; k0 += 16) {
            {   // load A: W[m0+m][k0+k]
                int k = tid & 15, mb = tid >> 4;
                #pragma unroll
                for (int j = 0; j < 4; j++)
                    As[k][mb + 16*j] = W[(size_t)(m0 + mb + 16*j) * SDIM + k0 + k];
            }
            {   // load B: Q[k0+k][n0+n]
                int n = tid & 63, kb = tid >> 6;
                #pragma unroll
                for (int j = 0; j < 4; j++)
                    Bs[kb + 4*j][n] = Q[(size_t)(k0 + kb + 4*j) * N_STATES + n0 + n];
            }
            __syncthreads();
            #pragma unroll
            for (int kk = 0; kk < 16; kk++) {
                float a[4], bb[4];
                #pragma unroll
                for (int i = 0; i < 4; i++) a[i] = As[kk][ty*4 + i];
                #pragma unroll
                for (int j = 0; j < 4; j++) bb[j] = Bs[kk][tx*4 + j];
                #pragma unroll
                for (int i = 0; i < 4; i++)
                    #pragma unroll
                    for (int j = 0; j < 4; j++)
                        c[i][j] += a[i] * bb[j];
            }
            __syncthreads();
        }
        #pragma unroll
        for (int i = 0; i < 4; i++) {
            int d = m0 + ty*4 + i;
            #pragma unroll
            for (int j = 0; j < 4; j++) {
                int s = n0 + tx*4 + j;
                float sn, cs;
                sincosf(c[i][j], &sn, &cs);
                cosQ[(size_t)d * N_STATES + s] = cs;
                sinQ[(size_t)d * N_STATES + s] = sn;
            }
        }
    } else if (b == NB_GEMM) {
        // ---- v = V @ action ----
        float acc = 0.f;
        for (int a = 0; a < N_ACT; a++) acc += V[tid * N_ACT + a] * action[a];
        vout[tid] = acc;
    } else {
        // ---- state0 partials: row d, segment seg of 1024 float4s ----
        const int bb = b - (NB_GEMM + 1);
        const int d = bb / 5;
        const int seg = bb - d * 5;
        const float* mr = Mre + (size_t)d * N_OBS;
        const float* mi = Mim + (size_t)d * N_OBS;
        const float4* ob = (const float4*)obs;
        float ar[4] = {}, ai[4] = {};
        #pragma unroll
        for (int it = 0; it < 4; ++it) {
            int i = seg * 1024 + it * 256 + tid;
            bool ok = i < N_OBS4;
            int ic = ok ? i : 0;
            float4 o = ok ? ob[ic] : make_float4(0.f, 0.f, 0.f, 0.f);
            v4f a = ntload4(mr + 4 * (size_t)ic);
            v4f m = ntload4(mi + 4 * (size_t)ic);
            ar[it] += a.x*o.x + a.y*o.y + a.z*o.z + a.w*o.w;
            ai[it] += m.x*o.x + m.y*o.y + m.z*o.z + m.w*o.w;
        }
        float arr = (ar[0] + ar[1]) + (ar[2] + ar[3]);
        float aii = (ai[0] + ai[1]) + (ai[2] + ai[3]);
        #pragma unroll
        for (int off = 32; off > 0; off >>= 1) {
            arr += __shfl_down(arr, off);
            aii += __shfl_down(aii, off);
        }
        __shared__ float pr[4], pi[4];
        const int wave = tid >> 6, lane = tid & 63;
        if (lane == 0) { pr[wave] = arr; pi[wave] = aii; }
        __syncthreads();
        if (tid == 0) {
            p0re[seg * RFD + d] = pr[0] + pr[1] + pr[2] + pr[3];
            p0im[seg * RFD + d] = pi[0] + pi[1] + pi[2] + pi[3];
        }
    }
}

// K2: one wave per row d: theta_v[d] = W[d,:]@v (coalesced float4 + shuffle),
// sum state0 partials -> s0; s1 = s0 * e^{i theta_v}. 512 blocks x 256 (4 waves).
__global__ __launch_bounds__(256) void k_state1(
    const float* __restrict__ W, const float* __restrict__ vws,
    const float* __restrict__ p0re, const float* __restrict__ p0im,
    float* __restrict__ s0re, float* __restrict__ s0im,
    float* __restrict__ s1re, float* __restrict__ s1im)
{
    const int tid = threadIdx.x;
    const int w = tid >> 6, l = tid & 63;
    const int d = blockIdx.x * 4 + w;
    float4 wv = ((const float4*)(W + (size_t)d * SDIM))[l];
    float4 vv = ((const float4*)vws)[l];
    float th = wv.x*vv.x + wv.y*vv.y + wv.z*vv.z + wv.w*vv.w;
    #pragma unroll
    for (int off = 32; off > 0; off >>= 1) th += __shfl_down(th, off);
    if (l == 0) {
        float re = 0.f, im = 0.f;
        #pragma unroll
        for (int s = 0; s < 5; s++) {
            re += p0re[s * RFD + d];
            im += p0im[s * RFD + d];
        }
        s0re[d] = re; s0im[d] = im;
        float sn, cs;
        sincosf(th, &sn, &cs);
        s1re[d] = re * cs - im * sn;
        s1im[d] = re * sn + im * cs;
    }
}

// K3: score[s] = sum_d cos[d,s]*s1re[d] + sin[d,s]*s1im[d]. grid (4,64), 32 rows/block.
__global__ __launch_bounds__(256) void k_score(
    const float* __restrict__ cosQ, const float* __restrict__ sinQ,
    const float* __restrict__ s1re, const float* __restrict__ s1im,
    float* __restrict__ score)
{
    const int s = blockIdx.x * 256 + threadIdx.x;
    const int d0 = blockIdx.y * 32;
    float acc = 0.f;
    #pragma unroll 4
    for (int j = 0; j < 32; j++) {
        int d = d0 + j;
        acc += cosQ[(size_t)d * N_STATES + s] * s1re[d]
             + sinQ[(size_t)d * N_STATES + s] * s1im[d];
    }
    atomicAdd(&score[s], acc);
}

// K4: weights = softmax(score / 2048), 1024 entries, single block of 256
__global__ __launch_bounds__(256) void k_softmax_w(
    const float* __restrict__ score, float* __restrict__ wts)
{
    __shared__ float red[256];
    const int tid = threadIdx.x;
    const float scale = 1.f / (float)RFD;
    float4 v = ((const float4*)score)[tid];
    v.x *= scale; v.y *= scale; v.z *= scale; v.w *= scale;
    float mx = fmaxf(fmaxf(v.x, v.y), fmaxf(v.z, v.w));
    red[tid] = mx; __syncthreads();
    for (int s = 128; s > 0; s >>= 1) {
        if (tid < s) red[tid] = fmaxf(red[tid], red[tid+s]);
        __syncthreads();
    }
    mx = red[0]; __syncthreads();
    float4 e;
    e.x = expf(v.x - mx); e.y = expf(v.y - mx);
    e.z = expf(v.z - mx); e.w = expf(v.w - mx);
    red[tid] = e.x + e.y + e.z + e.w; __syncthreads();
    for (int s = 128; s > 0; s >>= 1) {
        if (tid < s) red[tid] += red[tid+s];
        __syncthreads();
    }
    const float inv = 1.f / red[0];
    e.x *= inv; e.y *= inv; e.z *= inv; e.w *= inv;
    ((float4*)wts)[tid] = e;
}

// K5: state2 = phi_Q @ weights. Block per row d.
__global__ __launch_bounds__(256) void k_state2(
    const float* __restrict__ cosQ, const float* __restrict__ sinQ,
    const float* __restrict__ wts,
    float* __restrict__ s2re, float* __restrict__ s2im)
{
    __shared__ float r1[256], r2[256];
    const int d = blockIdx.x, tid = threadIdx.x;
    float4 w = ((const float4*)wts)[tid];
    float4 a = ((const float4*)(cosQ + (size_t)d * N_STATES))[tid];
    float4 b = ((const float4*)(sinQ + (size_t)d * N_STATES))[tid];
    r1[tid] = a.x*w.x + a.y*w.y + a.z*w.z + a.w*w.w;
    r2[tid] = b.x*w.x + b.y*w.y + b.z*w.z + b.w*w.w;
    __syncthreads();
    for (int s = 128; s > 0; s >>= 1) {
        if (tid < s) { r1[tid] += r1[tid+s]; r2[tid] += r2[tid+s]; }
        __syncthreads();
    }
    if (tid == 0) { s2re[d] = r1[0]; s2im[d] = r2[0]; }
}

// K6: obs_acc[o] += sum_{d in chunk of 16} Mre[d,o]*s2re[d] + Mim[d,o]*s2im[d]
// grid (20, 128), 256 threads, float4 over o, nt loads, 4 independent acc chains.
__global__ __launch_bounds__(256) void k_obs_acc(
    const float* __restrict__ Mre, const float* __restrict__ Mim,
    const float* __restrict__ s2re, const float* __restrict__ s2im,
    float* __restrict__ obs_acc)
{
    __shared__ float c_s[16], s_s[16];
    const int tid = threadIdx.x;
    const int dbase = blockIdx.y * 16;
    if (tid < 16) { c_s[tid] = s2re[dbase + tid]; s_s[tid] = s2im[dbase + tid]; }
    __syncthreads();
    const int idx = blockIdx.x * 256 + tid;   // float4 index into a row
    if (idx < N_OBS4) {
        float4 acc[4];
        #pragma unroll
        for (int u = 0; u < 4; u++) acc[u] = make_float4(0.f, 0.f, 0.f, 0.f);
        #pragma unroll
        for (int j = 0; j < 16; j++) {
            size_t base = ((size_t)(dbase + j) * N_OBS4 + idx) * 4;
            v4f a = ntload4(Mre + base);
            v4f b = ntload4(Mim + base);
            float cc = c_s[j], ss = s_s[j];
            int u = j & 3;
            acc[u].x += a.x*cc + b.x*ss;
            acc[u].y += a.y*cc + b.y*ss;
            acc[u].z += a.z*cc + b.z*ss;
            acc[u].w += a.w*cc + b.w*ss;
        }
        float4 t;
        t.x = (acc[0].x + acc[1].x) + (acc[2].x + acc[3].x);
        t.y = (acc[0].y + acc[1].y) + (acc[2].y + acc[3].y);
        t.z = (acc[0].z + acc[1].z) + (acc[2].z + acc[3].z);
        t.w = (acc[0].w + acc[1].w) + (acc[2].w + acc[3].w);
        atomicAdd(&obs_acc[idx*4 + 0], t.x);
        atomicAdd(&obs_acc[idx*4 + 1], t.y);
        atomicAdd(&obs_acc[idx*4 + 2], t.z);
        atomicAdd(&obs_acc[idx*4 + 3], t.w);
    }
}

// K7: dot0 = Re(s0 . conj(s2)); out = softmax((0.9*obs_acc + obs*dot0)/2048).
__global__ __launch_bounds__(1024) void k_softmax_obs(
    const float* __restrict__ obs_acc, const float* __restrict__ obs,
    const float* __restrict__ s0re, const float* __restrict__ s0im,
    const float* __restrict__ s2re, const float* __restrict__ s2im,
    float* __restrict__ out)
{
    __shared__ float red[1024];
    const int tid = threadIdx.x;
    float dp = 0.f;
    #pragma unroll
    for (int i = 0; i < 2; i++) {
        int d = tid + i * 1024;
        dp += s0re[d] * s2re[d] + s0im[d] * s2im[d];
    }
    red[tid] = dp; __syncthreads();
    for (int s = 512; s > 0; s >>= 1) {
        if (tid < s) red[tid] += red[tid+s];
        __syncthreads();
    }
    const float d0 = red[0];
    __syncthreads();
    const float scale = 1.f / (float)RFD;
    float vals[20];
    float mx = -3.402823466e+38f;
    #pragma unroll
    for (int i = 0; i < 20; i++) {
        int idx = tid + i * 1024;
        if (idx < N_OBS) {
            float sc = (DECAY * obs_acc[idx] + obs[idx] * d0) * scale;
            vals[i] = sc;
            mx = fmaxf(mx, sc);
        } else vals[i] = -3.402823466e+38f;
    }
    red[tid] = mx; __syncthreads();
    for (int s = 512; s > 0; s >>= 1) {
        if (tid < s) red[tid] = fmaxf(red[tid], red[tid+s]);
        __syncthreads();
    }
    mx = red[0]; __syncthreads();
    float sum = 0.f;
    #pragma unroll
    for (int i = 0; i < 20; i++) {
        int idx = tid + i * 1024;
        if (idx < N_OBS) {
            vals[i] = expf(vals[i] - mx);
            sum += vals[i];
        }
    }
    red[tid] = sum; __syncthreads();
    for (int s = 512; s > 0; s >>= 1) {
        if (tid < s) red[tid] += red[tid+s];
        __syncthreads();
    }
    const float inv = 1.f / red[0];
    #pragma unroll
    for (int i = 0; i < 20; i++) {
        int idx = tid + i * 1024;
        if (idx < N_OBS) out[idx] = vals[i] * inv;
    }
}

extern "C" void kernel_launch(void* const* d_in, const int* in_sizes, int n_in,
                              void* d_out, int out_size, void* d_ws, size_t ws_size,
                              hipStream_t stream) {
    const float* Q      = (const float*)d_in[0];  // [256,1024]
    const float* V      = (const float*)d_in[1];  // [256,64]
    const float* W      = (const float*)d_in[2];  // [2048,256]
    const float* Mre    = (const float*)d_in[3];  // [2048,20000]
    const float* Mim    = (const float*)d_in[4];  // [2048,20000]
    const float* obs    = (const float*)d_in[5];  // [20000]
    const float* action = (const float*)d_in[6];  // [64]
    float* out = (float*)d_out;                   // [20000]
    float* ws  = (float*)d_ws;

    if (ws_size < (size_t)WS_FLOATS * sizeof(float)) return;

    float* score = ws + OFF_SCORE;
    float* oacc  = ws + OFF_OBSACC;
    float* s0re  = ws + OFF_S0RE;
    float* s0im  = ws + OFF_S0IM;
    float* s1re  = ws + OFF_S1RE;
    float* s1im  = ws + OFF_S1IM;
    float* s2re  = ws + OFF_S2RE;
    float* s2im  = ws + OFF_S2IM;
    float* wts   = ws + OFF_WTS;
    float* vws   = ws + OFF_VWS;
    float* cosQ  = ws + OFF_COSQ;
    float* sinQ  = ws + OFF_SINQ;
    float* p0re  = ws + OFF_P0RE;
    float* p0im  = ws + OFF_P0IM;

    // zero the atomic accumulators (score, obs_acc) in one contiguous memset
    hipMemsetAsync(ws, 0, (size_t)ZERO_CNT * sizeof(float), stream);

    k_fused<<<NB_FUSED, 256, 0, stream>>>(Mre, Mim, obs, W, Q, V, action,
                                          cosQ, sinQ, p0re, p0im, vws);
    k_state1<<<RFD / 4, 256, 0, stream>>>(W, vws, p0re, p0im, s0re, s0im, s1re, s1im);
    k_score<<<dim3(4, 64), 256, 0, stream>>>(cosQ, sinQ, s1re, s1im, score);
    k_softmax_w<<<1, 256, 0, stream>>>(score, wts);
    k_state2<<<RFD, 256, 0, stream>>>(cosQ, sinQ, wts, s2re, s2im);
    k_obs_acc<<<dim3((N_OBS4 + 255) / 256, RFD / 16), 256, 0, stream>>>(Mre, Mim, s2re, s2im, oacc);
    k_softmax_obs<<<1, 1024, 0, stream>>>(oacc, obs, s0re, s0im, s2re, s2im, out);
}